// Round 7
// baseline (248.203 us; speedup 1.0000x reference)
//
#include <hip/hip_runtime.h>
#include <math.h>

// Problem constants (GPT2 decode attention, fp32)
#define BATCH   32
#define NH      16
#define HD      64      // head dim
#define T_ALL   2048    // cached 2047 + 1 new
#define T_CACHE 2047
#define HID     1024
#define H3      3072
#define QK_SCALE 0.125f // 64^-0.5
#define NCHUNK  16      // token chunks per (b,h); one chunk per 4-wave block
#define CHTOK   128     // tokens per chunk (32 per wave)
#define NWIN    8       // 4-token windows per wave (32 tokens/wave)
#define KSPLIT  8       // k-split for the GEMV kernels

// native 16B vector
typedef float f4 __attribute__((ext_vector_type(4)));

// ---------------------------------------------------------------------------
// GEMV part: out_part[ks][b][c] = sum_{k in split ks} X[b][k] * W[k][c]
// batch split across blockIdx.z; per-column k-order unchanged -> bit-exact.
// ---------------------------------------------------------------------------
template<int NB>
__global__ __launch_bounds__(256) void gemv_part_kernel(
    const float* __restrict__ X, const float* __restrict__ W,
    float* __restrict__ part, int N, int Kdim)
{
    const int c  = blockIdx.x * 256 + threadIdx.x;
    const int ks = blockIdx.y;
    const int b0 = blockIdx.z * NB;
    const int kchunk = Kdim / KSPLIT;
    float acc[NB];
#pragma unroll
    for (int j = 0; j < NB; ++j) acc[j] = 0.f;
    const int k0 = ks * kchunk;
#pragma unroll 16
    for (int k = k0; k < k0 + kchunk; ++k) {
        const float w = W[(size_t)k * N + c];
#pragma unroll
        for (int j = 0; j < NB; ++j)
            acc[j] = fmaf(X[(b0 + j) * Kdim + k], w, acc[j]);
    }
#pragma unroll
    for (int j = 0; j < NB; ++j)
        part[((size_t)ks * BATCH + b0 + j) * N + c] = acc[j];
}

// float4 reduce (bit-exact per element: bias first, then ks ascending)
__global__ __launch_bounds__(256) void gemv_reduce_kernel(
    const float* __restrict__ part, const float* __restrict__ bias,
    float* __restrict__ out, int N)
{
    const int c4 = blockIdx.x * 256 + threadIdx.x;
    const int b  = blockIdx.y;
    const int N4 = N >> 2;
    f4 acc = ((const f4*)bias)[c4];
#pragma unroll
    for (int ks = 0; ks < KSPLIT; ++ks) {
        const f4 p = ((const f4*)part)[((size_t)ks * BATCH + b) * N4 + c4];
        acc.x += p.x; acc.y += p.y; acc.z += p.z; acc.w += p.w;
    }
    ((f4*)out)[(size_t)b * N4 + c4] = acc;
}

// ---------------------------------------------------------------------------
// v8 kernel A: K-stream pass. grid = (NCHUNK=16, NH, BATCH) = 8192 blocks,
// block = 256 (4 waves), wave owns 32 tokens = 8 windows.
// Copies K->Kout (1R+1W pure stream) and computes the full per-chunk softmax
// numerators: P = exp(s - chunk_max), Pm = chunk max, Pl = sum P.
// Only TWO HBM streams touch this kernel -> copy-class DRAM locality.
// ---------------------------------------------------------------------------
__global__ __launch_bounds__(256, 6) void k_copy_score_kernel(
    const float* __restrict__ kc, const float* __restrict__ qkv,
    const int* __restrict__ seq_lens,
    float* __restrict__ Kout,
    float* __restrict__ Pm, float* __restrict__ Pl, float* __restrict__ P)
{
    const int chunk = blockIdx.x;
    const int h     = blockIdx.y;
    const int b     = blockIdx.z;
    const int tid   = threadIdx.x;
    const int wave  = tid >> 6;
    const int lane  = tid & 63;
    const int dgrp  = lane & 15;   // which float4 of the 64-dim row
    const int tgrp  = lane >> 4;   // which of 4 tokens per window

    const int bh   = b * NH + h;
    const int vlim = min(seq_lens[b], T_CACHE);   // token 2047 -> combine

    const f4 q4 = ((const f4*)(qkv + (size_t)b * H3 + h * HD))[dgrp];

    const int t0 = chunk * CHTOK + wave * (NWIN * 4);
    const int tl = t0 + tgrp;
    const int nat  = min(NWIN, max(0, (vlim - t0 + 3) >> 2));
    const bool tail = (t0 + NWIN * 4 - 1 >= T_CACHE);  // single tail wave

    const f4* kbase = (const f4*)(kc + (size_t)bh * T_CACHE * HD) + (size_t)tl * 16 + dgrp;
    f4* Kb = (f4*)(Kout + (size_t)bh * T_ALL * HD) + (size_t)tl * 16 + dgrp;

    f4 kreg[NWIN];
    float s[NWIN];

    if (!tail) {
#pragma unroll
        for (int i = 0; i < NWIN; ++i)
            kreg[i] = __builtin_nontemporal_load(kbase + i * 64);
#pragma unroll
        for (int i = 0; i < NWIN; ++i) {
            __builtin_nontemporal_store(kreg[i], Kb + i * 64);
            s[i] = kreg[i].x * q4.x + kreg[i].y * q4.y
                 + kreg[i].z * q4.z + kreg[i].w * q4.w;
        }
    } else {
#pragma unroll
        for (int i = 0; i < NWIN; ++i) {
            const int t = tl + i * 4;
            kreg[i] = (f4){0.f, 0.f, 0.f, 0.f};
            if (t < T_CACHE)
                kreg[i] = __builtin_nontemporal_load(kbase + i * 64);
        }
#pragma unroll
        for (int i = 0; i < NWIN; ++i) {
            const int t = tl + i * 4;
            if (t < T_CACHE)
                __builtin_nontemporal_store(kreg[i], Kb + i * 64);
            s[i] = kreg[i].x * q4.x + kreg[i].y * q4.y
                 + kreg[i].z * q4.z + kreg[i].w * q4.w;
        }
    }

    // cross-lane dot reduction + masking
#pragma unroll
    for (int i = 0; i < NWIN; ++i) {
        if (i < nat) {
            float ss = s[i];
            ss += __shfl_xor(ss, 1);
            ss += __shfl_xor(ss, 2);
            ss += __shfl_xor(ss, 4);
            ss += __shfl_xor(ss, 8);
            s[i] = (tl + i * 4 < vlim) ? ss * QK_SCALE : -1e30f;
        }
    }

    // wave max -> chunk max via LDS
    float m = -1e30f;
#pragma unroll
    for (int i = 0; i < NWIN; ++i)
        if (i < nat) m = fmaxf(m, s[i]);
    m = fmaxf(m, __shfl_xor(m, 16));
    m = fmaxf(m, __shfl_xor(m, 32));

    __shared__ float sm[4], sl[4];
    if (lane == 0) sm[wave] = m;
    __syncthreads();
    const float mc = fmaxf(fmaxf(sm[0], sm[1]), fmaxf(sm[2], sm[3]));

    // weights with the shared chunk max; masked windows underflow to 0
    float l = 0.f;
#pragma unroll
    for (int i = 0; i < NWIN; ++i)
        if (i < nat) {
            const float p = __expf(s[i] - mc);
            s[i] = p;
            l += p;
        }
    l += __shfl_xor(l, 16); l += __shfl_xor(l, 32);  // wave total

    const int pb = bh * NCHUNK + chunk;
    if (dgrp == 0) {
#pragma unroll
        for (int i = 0; i < NWIN; ++i)
            if (i < nat)
                P[(size_t)pb * CHTOK + wave * (NWIN * 4) + i * 4 + tgrp] = s[i];
    }
    if (lane == 0) sl[wave] = l;
    __syncthreads();
    if (tid == 0) {
        Pm[pb] = mc;
        Pl[pb] = sl[0] + sl[1] + sl[2] + sl[3];
    }
}

// ---------------------------------------------------------------------------
// v8 kernel B: V-stream pass. Same grid/layout as kernel A.
// Loads its 8 p-weights first, then the stream loop is load->store->fma:
// structurally a 1R+1W copy kernel. Writes the per-chunk output partial Po
// (plain sum across waves: all waves share the chunk max from kernel A).
// ---------------------------------------------------------------------------
__global__ __launch_bounds__(256, 6) void v_copy_accum_kernel(
    const float* __restrict__ vc, const int* __restrict__ seq_lens,
    const float* __restrict__ P,
    float* __restrict__ Vout, float* __restrict__ Po)
{
    const int chunk = blockIdx.x;
    const int h     = blockIdx.y;
    const int b     = blockIdx.z;
    const int tid   = threadIdx.x;
    const int wave  = tid >> 6;
    const int lane  = tid & 63;
    const int dgrp  = lane & 15;
    const int tgrp  = lane >> 4;

    const int bh   = b * NH + h;
    const int vlim = min(seq_lens[b], T_CACHE);

    const int t0 = chunk * CHTOK + wave * (NWIN * 4);
    const int tl = t0 + tgrp;
    const int nat  = min(NWIN, max(0, (vlim - t0 + 3) >> 2));
    const bool tail = (t0 + NWIN * 4 - 1 >= T_CACHE);

    const f4* vbase = (const f4*)(vc + (size_t)bh * T_CACHE * HD) + (size_t)tl * 16 + dgrp;
    f4* Vb = (f4*)(Vout + (size_t)bh * T_ALL * HD) + (size_t)tl * 16 + dgrp;

    const int pb = bh * NCHUNK + chunk;

    // p-weights up front (scalar loads, broadcast across the 16 dgrp lanes)
    float pw[NWIN];
#pragma unroll
    for (int i = 0; i < NWIN; ++i) {
        pw[i] = 0.f;
        if (i < nat)
            pw[i] = P[(size_t)pb * CHTOK + wave * (NWIN * 4) + i * 4 + tgrp];
    }

    f4 vreg[NWIN];
    if (!tail) {
#pragma unroll
        for (int i = 0; i < NWIN; ++i)
            vreg[i] = __builtin_nontemporal_load(vbase + i * 64);
    } else {
#pragma unroll
        for (int i = 0; i < NWIN; ++i) {
            const int t = tl + i * 4;
            vreg[i] = (f4){0.f, 0.f, 0.f, 0.f};
            if (t < T_CACHE)
                vreg[i] = __builtin_nontemporal_load(vbase + i * 64);
        }
    }

    f4 o = {0.f, 0.f, 0.f, 0.f};
    if (!tail) {
#pragma unroll
        for (int i = 0; i < NWIN; ++i) {
            __builtin_nontemporal_store(vreg[i], Vb + i * 64);
            o.x = fmaf(pw[i], vreg[i].x, o.x);
            o.y = fmaf(pw[i], vreg[i].y, o.y);
            o.z = fmaf(pw[i], vreg[i].z, o.z);
            o.w = fmaf(pw[i], vreg[i].w, o.w);
        }
    } else {
#pragma unroll
        for (int i = 0; i < NWIN; ++i) {
            const int t = tl + i * 4;
            if (t < T_CACHE)
                __builtin_nontemporal_store(vreg[i], Vb + i * 64);
            o.x = fmaf(pw[i], vreg[i].x, o.x);
            o.y = fmaf(pw[i], vreg[i].y, o.y);
            o.z = fmaf(pw[i], vreg[i].z, o.z);
            o.w = fmaf(pw[i], vreg[i].w, o.w);
        }
    }

    // merge o across the 4 token groups within the wave
    o.x += __shfl_xor(o.x, 16); o.x += __shfl_xor(o.x, 32);
    o.y += __shfl_xor(o.y, 16); o.y += __shfl_xor(o.y, 32);
    o.z += __shfl_xor(o.z, 16); o.z += __shfl_xor(o.z, 32);
    o.w += __shfl_xor(o.w, 16); o.w += __shfl_xor(o.w, 32);

    __shared__ f4 so4[4][16];
    if (lane < 16) so4[wave][dgrp] = o;
    __syncthreads();

    if (tid < HD) {
        const int d = tid;
        const float* so = (const float*)so4;   // [4][64]
        const float oc = so[0*HD + d] + so[1*HD + d]
                       + so[2*HD + d] + so[3*HD + d];
        Po[(size_t)pb * HD + d] = oc;
    }
}

// ---------------------------------------------------------------------------
// Combine chunk partials + the always-visible new token; also append the new
// k/v row to the output caches. grid = 512 (b*NH+h), block = 64 (one wave).
// ---------------------------------------------------------------------------
__global__ __launch_bounds__(64) void combine_kernel(
    const float* __restrict__ qkv,
    const float* __restrict__ Pm, const float* __restrict__ Pl,
    const float* __restrict__ Po,
    float* __restrict__ attn, float* __restrict__ Kout, float* __restrict__ Vout)
{
    const int bh = blockIdx.x;
    const int b = bh >> 4, h = bh & 15;
    const int d = threadIdx.x;     // 0..63

    const float* qb = qkv + (size_t)b * H3;
    const float qd = qb[h * HD + d];
    const float kn = qb[HID  + h * HD + d];
    const float vn = qb[2*HID + h * HD + d];

    // append new token row (position T_ALL-1)
    Kout[((size_t)bh * T_ALL + (T_ALL - 1)) * HD + d] = kn;
    Vout[((size_t)bh * T_ALL + (T_ALL - 1)) * HD + d] = vn;

    // new-token score (always valid)
    float s = qd * kn;
    s += __shfl_xor(s, 1);
    s += __shfl_xor(s, 2);
    s += __shfl_xor(s, 4);
    s += __shfl_xor(s, 8);
    s += __shfl_xor(s, 16);
    s += __shfl_xor(s, 32);
    s *= QK_SCALE;

    float mg = s;
#pragma unroll
    for (int c = 0; c < NCHUNK; ++c)
        mg = fmaxf(mg, Pm[bh * NCHUNK + c]);

    float L   = __expf(s - mg);   // p_new
    float acc = L * vn;
#pragma unroll 8
    for (int c = 0; c < NCHUNK; ++c) {
        const float e = __expf(Pm[bh * NCHUNK + c] - mg);
        acc += Po[(size_t)(bh * NCHUNK + c) * HD + d] * e;
        L   += Pl[bh * NCHUNK + c] * e;
    }
    attn[(size_t)b * HID + h * HD + d] = acc / L;
}

// ---------------------------------------------------------------------------
extern "C" void kernel_launch(void* const* d_in, const int* in_sizes, int n_in,
                              void* d_out, int out_size, void* d_ws, size_t ws_size,
                              hipStream_t stream)
{
    const float* hs       = (const float*)d_in[0];   // [32,1,1024]
    const float* kc       = (const float*)d_in[1];   // [32,16,2047,64]
    const float* vc       = (const float*)d_in[2];   // [32,16,2047,64]
    // d_in[3] block_tables: unused by the reference math
    const int*   seq_lens = (const int*)d_in[4];     // [32]
    // d_in[5] max_seq_len: == 2048, hardcoded
    const float* W_attn   = (const float*)d_in[6];   // [1024,3072]
    const float* b_attn   = (const float*)d_in[7];   // [3072]
    const float* W_proj   = (const float*)d_in[8];   // [1024,1024]
    const float* b_proj   = (const float*)d_in[9];   // [1024]

    float* out_attn = (float*)d_out;                           // 32*1024
    float* Kout = out_attn + (size_t)BATCH * HID;              // 32*16*2048*64
    float* Vout = Kout + (size_t)BATCH * NH * T_ALL * HD;

    // workspace layout (floats), liveness-aliased:
    //   union (1048576): qkv_part [gemv1..reduce1] -> P [A..B]
    //                    -> proj_part [gemv2..reduce2]
    float* w = (float*)d_ws;
    float* w_union     = w;                        // 1048576 floats
    float* w_qkv_part  = w_union;                  // 786432
    float* w_P         = w_union;                  // 1048576
    float* w_proj_part = w_union;                  // 262144
    float* w_qkv       = w + 1048576;                          // 98304
    float* w_Pm        = w_qkv + (size_t)BATCH * H3;           // 8192
    float* w_Pl        = w_Pm + BATCH * NH * NCHUNK;           // 8192
    float* w_Po        = w_Pl + BATCH * NH * NCHUNK;           // 524288
    float* w_attnvec   = w_Po + (size_t)BATCH * NH * NCHUNK * HD; // 32768
    // total 1720320 floats = 6.88 MB

    // 1) qkv = hs @ W_attn + b_attn
    gemv_part_kernel<16><<<dim3(H3 / 256, KSPLIT, 2), 256, 0, stream>>>(
        hs, W_attn, w_qkv_part, H3, HID);
    gemv_reduce_kernel<<<dim3(H3 / 4 / 256, BATCH), 256, 0, stream>>>(
        w_qkv_part, b_attn, w_qkv, H3);

    // 2a) K-stream: copy + scores + chunk softmax numerators
    k_copy_score_kernel<<<dim3(NCHUNK, NH, BATCH), 256, 0, stream>>>(
        kc, w_qkv, seq_lens, Kout, w_Pm, w_Pl, w_P);

    // 2b) V-stream: copy + weighted accumulate
    v_copy_accum_kernel<<<dim3(NCHUNK, NH, BATCH), 256, 0, stream>>>(
        vc, seq_lens, w_P, Vout, w_Po);

    // 3) combine partials + new token, append new k/v rows
    combine_kernel<<<dim3(BATCH * NH), 64, 0, stream>>>(
        w_qkv, w_Pm, w_Pl, w_Po, w_attnvec, Kout, Vout);

    // 4) out = attn @ W_proj + b_proj
    gemv_part_kernel<8><<<dim3(HID / 256, KSPLIT, 4), 256, 0, stream>>>(
        w_attnvec, W_proj, w_proj_part, HID, HID);
    gemv_reduce_kernel<<<dim3(HID / 4 / 256, BATCH), 256, 0, stream>>>(
        w_proj_part, b_proj, out_attn, HID);
}